// Round 4
// baseline (233.856 us; speedup 1.0000x reference)
//
#include <hip/hip_runtime.h>

// RetrievalHeadPyramidBottomUpInstantSimple
// feat0 [32,256,56,56], feat1 [32,512,28,28], feat2 [32,1024,14,14],
// feat3 [32,2048,7,7], conv_w [1024,3840]  (all fp32) -> out [32,1024] fp32
//
// Identity: jax bilinear half-pixel upsample by integer factor to 56x56 has
// exactly-uniform per-input-pixel weight column sums, so
// mean(upsample(f)) == mean(f).  Hence:
//   out = concat_l(spatial_mean(feat_l)) @ conv_w^T
//
// R3 post-mortem: pool latency-bound (VGPR=12 serialized loads, VALUBusy 8%).
// R4: unified segment pool — every plane size divides into 49-float segments;
// each block stages 50176 B (256 segs) via async global_load_lds (12 x 1KB
// rounds per wave, single waitcnt+barrier), per-thread LDS segment sum
// (stride 49 words -> 2-way = free), plane sums via pure shuffles.

#define AS1(p) ((const __attribute__((address_space(1))) void*)(p))
#define AS3(p) ((__attribute__((address_space(3))) void*)(p))

__global__ __launch_bounds__(256) void pool_kernel(
    const float* __restrict__ f0, const float* __restrict__ f1,
    const float* __restrict__ f2, const float* __restrict__ f3,
    float* __restrict__ v)
{
    __shared__ float l[12544];              // 50176 B -> 3 blocks/CU
    int bid = blockIdx.x, t = threadIdx.x;
    int wave = t >> 6, lane = t & 63;

    // route: 2048 f0 blocks, 1024 f1, 512 f2, 256 f3 (each covers 12544 floats)
    const float* base;
    if (bid < 2048)      base = f0 + (size_t)bid * 12544;
    else if (bid < 3072) base = f1 + (size_t)(bid - 2048) * 12544;
    else if (bid < 3584) base = f2 + (size_t)(bid - 3072) * 12544;
    else                 base = f3 + (size_t)(bid - 3584) * 12544;

    // ---- async stage: each wave moves 3136 floats (12.25 KB) ----
    {
        const float* g = base + wave * 3136;
        float* ld = l + wave * 3136;
        #pragma unroll
        for (int r = 0; r < 12; ++r) {
            __builtin_amdgcn_global_load_lds(
                AS1(g + r * 256 + lane * 4), AS3(ld + r * 256), 16, 0, 0);
        }
        if (lane < 16) {
            __builtin_amdgcn_global_load_lds(
                AS1(g + 3072 + lane * 4), AS3(ld + 3072), 16, 0, 0);
        }
    }
    asm volatile("s_waitcnt vmcnt(0)" ::: "memory");
    __syncthreads();

    // ---- per-thread 49-float segment sum (2-way bank alias = free) ----
    const float* seg = l + t * 49;
    float s = 0.f;
    #pragma unroll
    for (int i = 0; i < 49; ++i) s += seg[i];

    // ---- plane combine via shuffles + write ----
    if (bid < 2048) {
        // 4 planes/block, plane == wave (64 segs)
        #pragma unroll
        for (int o = 32; o; o >>= 1) s += __shfl_xor(s, o);
        if (lane == 0) {
            int q = bid * 4 + wave;                    // f0 plane id
            v[(q >> 8) * 3840 + (q & 255)] = s * (1.f / 3136.f);
        }
    } else if (bid < 3072) {
        // 16 planes/block, plane == 16-lane group
        s += __shfl_xor(s, 8); s += __shfl_xor(s, 4);
        s += __shfl_xor(s, 2); s += __shfl_xor(s, 1);
        if ((t & 15) == 0) {
            int q = (bid - 2048) * 16 + (t >> 4);      // f1 plane id
            v[(q >> 9) * 3840 + 256 + (q & 511)] = s * (1.f / 784.f);
        }
    } else if (bid < 3584) {
        // 64 planes/block, plane == 4-lane group
        s += __shfl_xor(s, 2); s += __shfl_xor(s, 1);
        if ((t & 3) == 0) {
            int q = (bid - 3072) * 64 + (t >> 2);      // f2 plane id
            v[(q >> 10) * 3840 + 768 + (q & 1023)] = s * (1.f / 196.f);
        }
    } else {
        // 256 planes/block, plane == thread
        int q = (bid - 3584) * 256 + t;                // f3 plane id
        v[(q >> 11) * 3840 + 1792 + (q & 2047)] = s * (1.f / 49.f);
    }
}

// GEMM: out[b,e] = sum_k v[b,k]*W[e,k]; M=32,N=1024,K=3840
// e-tile 64, split-K x32 (KT=120) -> grid 512 blocks.
#define KT 120

__global__ __launch_bounds__(256) void gemm_kernel(
    const float* __restrict__ v, const float* __restrict__ W,
    float* __restrict__ partials)
{
    __shared__ float vs[32][124];
    __shared__ float wsh[64][124];
    int t = threadIdx.x;
    int et = blockIdx.x & 15, ks = blockIdx.x >> 4;
    int e0 = et << 6, k0 = ks * KT;

    // stage W tile: 64 rows x 30 f4 = 1920 f4 — batch loads, then writes
    {
        float4 tmp[7];
        int row[7], c4[7];
        #pragma unroll
        for (int i = 0; i < 7; ++i) {
            int f = t + (i << 8);
            row[i] = f / 30; c4[i] = f % 30;
            tmp[i] = *(const float4*)&W[(size_t)(e0 + row[i]) * 3840 + k0 + c4[i] * 4];
        }
        float4 tail; int rowt = 0, c4t = 0;
        if (t < 128) {
            int f = t + 1792;
            rowt = f / 30; c4t = f % 30;
            tail = *(const float4*)&W[(size_t)(e0 + rowt) * 3840 + k0 + c4t * 4];
        }
        #pragma unroll
        for (int i = 0; i < 7; ++i)
            *(float4*)&wsh[row[i]][c4[i] * 4] = tmp[i];
        if (t < 128)
            *(float4*)&wsh[rowt][c4t * 4] = tail;
    }
    // stage v tile: 32 rows x 30 f4 = 960 f4
    {
        float4 tmp[3];
        int row[3], c4[3];
        #pragma unroll
        for (int i = 0; i < 3; ++i) {
            int f = t + (i << 8);
            row[i] = f / 30; c4[i] = f % 30;
            tmp[i] = *(const float4*)&v[row[i] * 3840 + k0 + c4[i] * 4];
        }
        float4 tail; int rowt = 0, c4t = 0;
        if (t < 192) {
            int f = t + 768;
            rowt = f / 30; c4t = f % 30;
            tail = *(const float4*)&v[rowt * 3840 + k0 + c4t * 4];
        }
        #pragma unroll
        for (int i = 0; i < 3; ++i)
            *(float4*)&vs[row[i]][c4[i] * 4] = tmp[i];
        if (t < 192)
            *(float4*)&vs[rowt][c4t * 4] = tail;
    }
    __syncthreads();

    int bg = t >> 5, eg = t & 31;
    int b0 = bg << 2;
    float acc[4][2] = {};
    #pragma unroll 5
    for (int k = 0; k < KT; k += 4) {
        float4 vv[4], ww[2];
        #pragma unroll
        for (int i = 0; i < 4; ++i) vv[i] = *(const float4*)&vs[b0 + i][k];
        #pragma unroll
        for (int j = 0; j < 2; ++j) ww[j] = *(const float4*)&wsh[eg + (j << 5)][k];
        #pragma unroll
        for (int i = 0; i < 4; ++i)
            #pragma unroll
            for (int j = 0; j < 2; ++j)
                acc[i][j] += vv[i].x * ww[j].x + vv[i].y * ww[j].y +
                             vv[i].z * ww[j].z + vv[i].w * ww[j].w;
    }

    float* pout = partials + (size_t)ks * 32768 + (size_t)b0 * 1024 + e0 + eg;
    #pragma unroll
    for (int i = 0; i < 4; ++i)
        #pragma unroll
        for (int j = 0; j < 2; ++j)
            pout[i * 1024 + (j << 5)] = acc[i][j];
}

__global__ __launch_bounds__(256) void reduce_kernel(
    const float* __restrict__ partials, float* __restrict__ out)
{
    int idx = blockIdx.x * 256 + threadIdx.x;  // 0..32767
    float s0 = 0.f, s1 = 0.f, s2 = 0.f, s3 = 0.f;
    #pragma unroll
    for (int sp = 0; sp < 32; sp += 4) {
        s0 += partials[(sp + 0) * 32768 + idx];
        s1 += partials[(sp + 1) * 32768 + idx];
        s2 += partials[(sp + 2) * 32768 + idx];
        s3 += partials[(sp + 3) * 32768 + idx];
    }
    out[idx] = (s0 + s1) + (s2 + s3);
}

extern "C" void kernel_launch(void* const* d_in, const int* in_sizes, int n_in,
                              void* d_out, int out_size, void* d_ws, size_t ws_size,
                              hipStream_t stream)
{
    const float* f0 = (const float*)d_in[0];
    const float* f1 = (const float*)d_in[1];
    const float* f2 = (const float*)d_in[2];
    const float* f3 = (const float*)d_in[3];
    const float* W  = (const float*)d_in[4];
    float* out = (float*)d_out;

    float* v        = (float*)d_ws;      // 32*3840 floats
    float* partials = v + 32 * 3840;     // 32*32768 floats = 4 MB

    pool_kernel<<<3840, 256, 0, stream>>>(f0, f1, f2, f3, v);
    gemm_kernel<<<512, 256, 0, stream>>>(v, W, partials);
    reduce_kernel<<<128, 256, 0, stream>>>(partials, out);
}